// Round 1
// baseline (139.328 us; speedup 1.0000x reference)
//
#include <hip/hip_runtime.h>
#include <hip/hip_bf16.h>
#include <stdint.h>

#define AS1 __attribute__((address_space(1)))
#define AS3 __attribute__((address_space(3)))

typedef float  f32x4  __attribute__((ext_vector_type(4)));
typedef __bf16 bf16x8 __attribute__((ext_vector_type(8)));
typedef __bf16 bf16x2 __attribute__((ext_vector_type(2)));
typedef short  s16x8  __attribute__((ext_vector_type(8)));

static constexpr int Bc = 16, Sc = 512, Hc = 768, NSPAN = 4068;
static constexpr int BM = 128, BN = 128, BK = 64, KS = Hc / BK; // 12 k-steps

static __device__ __forceinline__ uint32_t pack2bf(float x, float y) {
  bf16x2 p;
  p[0] = (__bf16)x;
  p[1] = (__bf16)y;
  return __builtin_bit_cast(uint32_t, p);
}

// ---------------- prep: W1^T -> bf16, chunk-swizzled (16B chunks XORed by n&7 within 128B groups) ----------------
__global__ __launch_bounds__(256)
void prep_w1t(const float* __restrict__ w_lin, unsigned short* __restrict__ w1t) {
  __shared__ __align__(16) unsigned short T[64][80]; // [n_local][k_local], padded rows (160B, 16B-aligned)
  int bidk = blockIdx.x % 12, bidn = blockIdx.x / 12;
  int k0 = bidk * 64, n0 = bidn * 64;
  int tid = threadIdx.x;
#pragma unroll
  for (int p = 0; p < 16; ++p) {
    int idx = p * 256 + tid;
    int kl = idx >> 6, nl = idx & 63;
    float v = w_lin[(size_t)(k0 + kl) * Hc + (n0 + nl)];
    __bf16 bv = (__bf16)v;
    T[nl][kl] = __builtin_bit_cast(unsigned short, bv);
  }
  __syncthreads();
#pragma unroll
  for (int qq = 0; qq < 2; ++qq) {
    int q = qq * 256 + tid;
    int nl = q >> 3, c = q & 7;
    int n = n0 + nl;
    int gp = (k0 >> 3) + (c ^ (n & 7)); // swizzled chunk position within aligned 8-chunk group
    s16x8 v = *(const s16x8*)(&T[nl][c * 8]);
    *(s16x8*)(w1t + (size_t)n * Hc + gp * 8) = v;
  }
}

// ---------------- cls projection (fp32 exact, bias folded) + token_inputs copy ----------------
__global__ __launch_bounds__(256)
void cls_proj_kernel(const float* __restrict__ emb, const float* __restrict__ w_lin,
                     const float* __restrict__ b_lin, float* __restrict__ out,
                     float* __restrict__ cls_proj) {
  __shared__ float cls_s[Hc];
  int b = blockIdx.x / 3, hc = blockIdx.x % 3;
  int tid = threadIdx.x;
  const float* cls = emb + (size_t)b * Sc * Hc; // row s=0
  for (int i = tid; i < Hc; i += 256) cls_s[i] = cls[i];
  __syncthreads();
  int h = hc * 256 + tid;
  const float* wp = w_lin + (size_t)Hc * Hc + h; // rows H..2H-1, column h
  float p0 = 0, p1 = 0, p2 = 0, p3 = 0, p4 = 0, p5 = 0, p6 = 0, p7 = 0;
  for (int f = 0; f < Hc; f += 8) {
    p0 += cls_s[f + 0] * wp[(size_t)(f + 0) * Hc];
    p1 += cls_s[f + 1] * wp[(size_t)(f + 1) * Hc];
    p2 += cls_s[f + 2] * wp[(size_t)(f + 2) * Hc];
    p3 += cls_s[f + 3] * wp[(size_t)(f + 3) * Hc];
    p4 += cls_s[f + 4] * wp[(size_t)(f + 4) * Hc];
    p5 += cls_s[f + 5] * wp[(size_t)(f + 5) * Hc];
    p6 += cls_s[f + 6] * wp[(size_t)(f + 6) * Hc];
    p7 += cls_s[f + 7] * wp[(size_t)(f + 7) * Hc];
  }
  float acc = b_lin[h] + (((p0 + p1) + (p2 + p3)) + ((p4 + p5) + (p6 + p7)));
  cls_proj[b * Hc + h] = acc;
  out[b * Hc + h] = cls_s[h]; // token_inputs
}

// ---------------- fused span-max + GEMM + epilogue ----------------
// Padded row space: m = (b*512 + s)*8 + (w-1), m in [0, 65536). Tile = 128 rows (16 starts, 1 batch).
__global__ __launch_bounds__(256, 2)
void span_gemm(const float* __restrict__ emb, const unsigned short* __restrict__ w1t,
               const float* __restrict__ cls_proj, const float* __restrict__ w_lin,
               float* __restrict__ out) {
  __shared__ __align__(16) float embS[24 * 64];            // [row][64 f32] k-slice of embeddings
  __shared__ __align__(16) unsigned short Ald[BM * BK];    // swizzled [m][64] bf16
  __shared__ __align__(16) unsigned short Bld[BN * BK];    // swizzled [n][64] bf16 (W1^T rows)

  int bid = blockIdx.x;
  int tile_n = bid % 6, tile_m = bid / 6;
  int b = tile_m >> 5;                 // 32 m-tiles per batch (4096 rows / 128)
  int s0 = (tile_m & 31) << 4;         // 16 starts per tile
  int n0 = tile_n * BN;
  int tid = threadIdx.x;
  int wid = tid >> 6, lane = tid & 63;
  int wave_m = wid >> 1, wave_n = wid & 1;
  int lq = lane >> 4, lr = lane & 15;

  const float* embB = emb + (size_t)b * Sc * Hc;

  f32x4 acc[4][4];
  f32x4 zer = {0.f, 0.f, 0.f, 0.f};
#pragma unroll
  for (int i = 0; i < 4; ++i)
#pragma unroll
    for (int j = 0; j < 4; ++j) acc[i][j] = zer;

  for (int ks = 0; ks < KS; ++ks) {
    int k0 = ks * BK;
    __syncthreads(); // previous iteration's LDS reads complete

    // ---- stage embeddings slice: 24 rows x 64 f32, global_load_lds width 16 ----
    {
      int t = wid; // waves 0..3 stage rows 4t..4t+3
      int r = s0 + (t << 2) + lq;
      if (r > 511) r = 511;
      const float* gp = embB + (size_t)r * Hc + k0 + (lr << 2);
      __builtin_amdgcn_global_load_lds((const AS1 uint32_t*)gp,
                                       (AS3 uint32_t*)(embS + (t << 8)), 16, 0, 0);
      if (wid < 2) { // waves 0,1 stage rows 16..23
        int t2 = 4 + wid;
        int r2 = s0 + (t2 << 2) + lq;
        if (r2 > 511) r2 = 511;
        const float* gp2 = embB + (size_t)r2 * Hc + k0 + (lr << 2);
        __builtin_amdgcn_global_load_lds((const AS1 uint32_t*)gp2,
                                         (AS3 uint32_t*)(embS + (t2 << 8)), 16, 0, 0);
      }
    }
    // ---- stage B tile: 128 rows x 64 bf16 from pre-swizzled w1t (linear dest => swizzled LDS) ----
#pragma unroll
    for (int j = 0; j < 4; ++j) {
      int u = (wid << 2) + j;
      int n = n0 + (u << 3) + (lane >> 3);
      const unsigned short* gp = w1t + (size_t)n * Hc + k0 + ((lane & 7) << 3);
      __builtin_amdgcn_global_load_lds((const AS1 uint32_t*)gp,
                                       (AS3 uint32_t*)(Bld + (u << 9)), 16, 0, 0);
    }
    __syncthreads(); // barrier drains vmcnt(0): staged data visible

    // ---- build A: running max over widths 1..8, 1 max + 1 pack per element, swizzled write ----
#pragma unroll
    for (int qq = 0; qq < 2; ++qq) {
      int q = (qq << 8) + tid;
      int i = q >> 5, kp = q & 31; // start-local i, k-pair kp (k = 2*kp)
      const float* ebase = embS + (kp << 1);
      float2 cm = *(const float2*)(ebase + (i << 6));
      {
        int mm = i << 3;
        uint32_t pk = pack2bf(cm.x, cm.y);
        int off = (mm << 7) + (((kp >> 2) ^ (mm & 7)) << 4) + ((kp & 3) << 2);
        *(uint32_t*)((char*)Ald + off) = pk;
      }
#pragma unroll
      for (int t = 1; t < 8; ++t) {
        float2 e = *(const float2*)(ebase + ((i + t) << 6));
        cm.x = fmaxf(cm.x, e.x);
        cm.y = fmaxf(cm.y, e.y);
        int mm = (i << 3) + t;
        uint32_t pk = pack2bf(cm.x, cm.y);
        int off = (mm << 7) + (((kp >> 2) ^ (mm & 7)) << 4) + ((kp & 3) << 2);
        *(uint32_t*)((char*)Ald + off) = pk;
      }
    }
    __syncthreads();

    // ---- MFMA: each wave 64x64, 4x4 frags of 16x16x32, 2 k-frags ----
#pragma unroll
    for (int kk = 0; kk < 2; ++kk) {
      bf16x8 af[4], bfr[4];
      int cf = (kk << 2) + lq; // 16B chunk index within 128B row
#pragma unroll
      for (int mi = 0; mi < 4; ++mi) {
        int m = (wave_m << 6) + (mi << 4) + lr;
        af[mi] = *(const bf16x8*)((const char*)Ald + (m << 7) + ((cf ^ (m & 7)) << 4));
      }
#pragma unroll
      for (int ni = 0; ni < 4; ++ni) {
        int n = (wave_n << 6) + (ni << 4) + lr;
        bfr[ni] = *(const bf16x8*)((const char*)Bld + (n << 7) + ((cf ^ (n & 7)) << 4));
      }
#pragma unroll
      for (int mi = 0; mi < 4; ++mi)
#pragma unroll
        for (int ni = 0; ni < 4; ++ni)
          acc[mi][ni] = __builtin_amdgcn_mfma_f32_16x16x32_bf16(af[mi], bfr[ni], acc[mi][ni], 0, 0, 0);
    }
  }

  // ---- epilogue: add cls_proj + width*w_last, map padded rows -> span index, store ----
  const float* w2p = w_lin + (size_t)(2 * Hc) * Hc; // row 2H of w_lin
  float* outp = out + Bc * Hc;                      // span_reps region
  int mb0 = tile_m << 7;
#pragma unroll
  for (int ni = 0; ni < 4; ++ni) {
    int h = n0 + (wave_n << 6) + (ni << 4) + lr;
    float cp = cls_proj[b * Hc + h];
    float w2 = w2p[h];
#pragma unroll
    for (int mi = 0; mi < 4; ++mi) {
#pragma unroll
      for (int j = 0; j < 4; ++j) {
        int mg = mb0 + (wave_m << 6) + (mi << 4) + (lq << 2) + j;
        int sw = mg & 4095;
        int s = sw >> 3, w = (sw & 7) + 1;
        if (s + w <= 512) {
          int nsp = (s <= 504) ? ((s << 3) + w - 1)
                               : (NSPAN - (((512 - s) * (513 - s)) >> 1) + w - 1);
          size_t oidx = ((size_t)b * NSPAN + nsp) * Hc + h;
          outp[oidx] = acc[mi][ni][j] + cp + (float)w * w2;
        }
      }
    }
  }
}

extern "C" void kernel_launch(void* const* d_in, const int* in_sizes, int n_in,
                              void* d_out, int out_size, void* d_ws, size_t ws_size,
                              hipStream_t stream) {
  const float* emb = (const float*)d_in[0];
  const float* w_lin = (const float*)d_in[1];
  const float* b_lin = (const float*)d_in[2];
  // d_in[3]/d_in[4] (span_starts/widths) are implied by the closed-form enumeration; unused.
  unsigned short* w1t = (unsigned short*)d_ws;                          // 768*768 bf16 = 1.18 MB
  float* cls_proj = (float*)((char*)d_ws + (size_t)Hc * Hc * 2);        // 16*768 f32
  float* out = (float*)d_out;

  hipLaunchKernelGGL(prep_w1t, dim3(144), dim3(256), 0, stream, w_lin, w1t);
  hipLaunchKernelGGL(cls_proj_kernel, dim3(48), dim3(256), 0, stream, emb, w_lin, b_lin, out, cls_proj);
  hipLaunchKernelGGL(span_gemm, dim3(512 * 6), dim3(256), 0, stream, emb, w1t, cls_proj, w_lin, out);
}

// Round 2
// 127.510 us; speedup vs baseline: 1.0927x; 1.0927x over previous
//
#include <hip/hip_runtime.h>
#include <hip/hip_bf16.h>
#include <stdint.h>

#define AS1 __attribute__((address_space(1)))
#define AS3 __attribute__((address_space(3)))

typedef float  f32x4  __attribute__((ext_vector_type(4)));
typedef __bf16 bf16x8 __attribute__((ext_vector_type(8)));
typedef __bf16 bf16x4 __attribute__((ext_vector_type(4)));
typedef short  s16x8  __attribute__((ext_vector_type(8)));

static constexpr int Bc = 16, Sc = 512, Hc = 768, NSPAN = 4068;
static constexpr int BM = 128, BN = 256, BK = 64, KS = Hc / BK; // 12 k-steps

// ---------------- prep: W1^T -> bf16, chunk-swizzled (16B chunks XORed by n&7 within 128B k-groups) ----------------
__global__ __launch_bounds__(256)
void prep_w1t(const float* __restrict__ w_lin, unsigned short* __restrict__ w1t) {
  __shared__ __align__(16) unsigned short T[64][80]; // [n_local][k_local], padded rows
  int bidk = blockIdx.x % 12, bidn = blockIdx.x / 12;
  int k0 = bidk * 64, n0 = bidn * 64;
  int tid = threadIdx.x;
#pragma unroll
  for (int p = 0; p < 16; ++p) {
    int idx = p * 256 + tid;
    int kl = idx >> 6, nl = idx & 63;
    float v = w_lin[(size_t)(k0 + kl) * Hc + (n0 + nl)];
    __bf16 bv = (__bf16)v;
    T[nl][kl] = __builtin_bit_cast(unsigned short, bv);
  }
  __syncthreads();
#pragma unroll
  for (int qq = 0; qq < 2; ++qq) {
    int q = qq * 256 + tid;
    int nl = q >> 3, c = q & 7;
    int n = n0 + nl;
    int gp = (k0 >> 3) + (c ^ (n & 7)); // swizzled chunk position within aligned 8-chunk group
    s16x8 v = *(const s16x8*)(&T[nl][c * 8]);
    *(s16x8*)(w1t + (size_t)n * Hc + gp * 8) = v;
  }
}

// ---------------- cls projection (fp32 exact, bias folded) + token_inputs copy ----------------
__global__ __launch_bounds__(256)
void cls_proj_kernel(const float* __restrict__ emb, const float* __restrict__ w_lin,
                     const float* __restrict__ b_lin, float* __restrict__ out,
                     float* __restrict__ cls_proj) {
  __shared__ float cls_s[Hc];
  int b = blockIdx.x / 3, hc = blockIdx.x % 3;
  int tid = threadIdx.x;
  const float* cls = emb + (size_t)b * Sc * Hc; // row s=0
  for (int i = tid; i < Hc; i += 256) cls_s[i] = cls[i];
  __syncthreads();
  int h = hc * 256 + tid;
  const float* wp = w_lin + (size_t)Hc * Hc + h; // rows H..2H-1, column h
  float p0 = 0, p1 = 0, p2 = 0, p3 = 0, p4 = 0, p5 = 0, p6 = 0, p7 = 0;
  for (int f = 0; f < Hc; f += 8) {
    p0 += cls_s[f + 0] * wp[(size_t)(f + 0) * Hc];
    p1 += cls_s[f + 1] * wp[(size_t)(f + 1) * Hc];
    p2 += cls_s[f + 2] * wp[(size_t)(f + 2) * Hc];
    p3 += cls_s[f + 3] * wp[(size_t)(f + 3) * Hc];
    p4 += cls_s[f + 4] * wp[(size_t)(f + 4) * Hc];
    p5 += cls_s[f + 5] * wp[(size_t)(f + 5) * Hc];
    p6 += cls_s[f + 6] * wp[(size_t)(f + 6) * Hc];
    p7 += cls_s[f + 7] * wp[(size_t)(f + 7) * Hc];
  }
  float acc = b_lin[h] + (((p0 + p1) + (p2 + p3)) + ((p4 + p5) + (p6 + p7)));
  cls_proj[b * Hc + h] = acc;
  out[b * Hc + h] = cls_s[h]; // token_inputs
}

// ---------------- fused span-max + GEMM + epilogue ----------------
// Padded row space: m = (b*512 + s)*8 + (w-1). Tile = 128 rows (16 starts) x 256 cols.
// 4 waves, each wave computes the FULL 128 rows x its 64-col slice (acc 8x4 f32x4).
__global__ __launch_bounds__(256, 2)
void span_gemm(const float* __restrict__ emb, const unsigned short* __restrict__ w1t,
               const float* __restrict__ cls_proj, const float* __restrict__ w_lin,
               float* __restrict__ out) {
  __shared__ __align__(16) unsigned short Ald[BM * BK]; // swizzled [m][64] bf16, 16 KB
  __shared__ __align__(16) unsigned short Bld[BN * BK]; // swizzled [n][64] bf16, 32 KB

  int bid = blockIdx.x;
  int tile_n = bid % 3, tile_m = bid / 3;
  int b = tile_m >> 5;                 // 32 m-tiles per batch (4096 rows / 128)
  int s0 = (tile_m & 31) << 4;         // 16 starts per tile
  int n0 = tile_n * BN;
  int tid = threadIdx.x;
  int wid = tid >> 6, lane = tid & 63;
  int lq = lane >> 4, lr = lane & 15;

  const char* embC = (const char*)(emb + (size_t)b * Sc * Hc);

  // A-build item: one per thread. start i = tid>>4 (0..15), k-quad kq = tid&15 (0..15).
  int bi = tid >> 4, bkq = tid & 15;
  uint32_t rowoff[8];
#pragma unroll
  for (int t = 0; t < 8; ++t) {
    int r = s0 + bi + t;
    if (r > 511) r = 511;                       // clamped rows feed only discarded outputs
    rowoff[t] = (uint32_t)r * (Hc * 4) + bkq * 16;
  }
  // A-write swizzle: m = bi*8+t -> byte = bi*1024 + t*128 + ((bkq>>1 ^ t)<<4) + (bkq&1)*8
  int awbase = (bi << 10) + ((bkq & 1) << 3);

  f32x4 acc[8][4];
  f32x4 zer = {0.f, 0.f, 0.f, 0.f};
#pragma unroll
  for (int i = 0; i < 8; ++i)
#pragma unroll
    for (int j = 0; j < 4; ++j) acc[i][j] = zer;

  for (int ks = 0; ks < KS; ++ks) {
    int k0 = ks * BK;

    // ---- issue A-build global loads (reg-staged; L2-resident) BEFORE the barrier ----
    f32x4 rv[8];
#pragma unroll
    for (int t = 0; t < 8; ++t)
      rv[t] = *(const f32x4*)(embC + rowoff[t] + k0 * 4);

    __syncthreads(); // previous iteration's LDS reads complete before overwrite

    // ---- stage B tile: 256 rows x 64 bf16 from pre-swizzled w1t (linear dest => swizzled LDS) ----
#pragma unroll
    for (int j = 0; j < 8; ++j) {
      int u = (wid << 3) + j;
      int n = n0 + (u << 3) + (lane >> 3);
      const unsigned short* gp = w1t + (size_t)n * Hc + k0 + ((lane & 7) << 3);
      __builtin_amdgcn_global_load_lds((const AS1 uint32_t*)gp,
                                       (AS3 uint32_t*)(Bld + (u << 9)), 16, 0, 0);
    }

    // ---- build A: running max over widths 1..8, one float4 per (row, k-quad), swizzled b64 writes ----
    {
      f32x4 cm = rv[0];
#pragma unroll
      for (int t = 0; t < 8; ++t) {
        if (t) {
          cm[0] = fmaxf(cm[0], rv[t][0]);
          cm[1] = fmaxf(cm[1], rv[t][1]);
          cm[2] = fmaxf(cm[2], rv[t][2]);
          cm[3] = fmaxf(cm[3], rv[t][3]);
        }
        bf16x4 p;
        p[0] = (__bf16)cm[0]; p[1] = (__bf16)cm[1];
        p[2] = (__bf16)cm[2]; p[3] = (__bf16)cm[3];
        int off = awbase + (t << 7) + ((((bkq >> 1) ^ t)) << 4);
        *(uint2*)((char*)Ald + off) = __builtin_bit_cast(uint2, p);
      }
    }

    __syncthreads(); // drains vmcnt(0): B staged; lgkm: A written

    // ---- MFMA: each wave 128x64, 8x4 frags of 16x16x32, 2 k-frags ----
#pragma unroll
    for (int kk = 0; kk < 2; ++kk) {
      bf16x8 af[8], bfr[4];
      int cf = (kk << 2) + lq; // 16B chunk index within 128B row
#pragma unroll
      for (int mi = 0; mi < 8; ++mi) {
        int m = (mi << 4) + lr;
        af[mi] = *(const bf16x8*)((const char*)Ald + (m << 7) + ((cf ^ (m & 7)) << 4));
      }
#pragma unroll
      for (int ni = 0; ni < 4; ++ni) {
        int n = (wid << 6) + (ni << 4) + lr;
        bfr[ni] = *(const bf16x8*)((const char*)Bld + (n << 7) + ((cf ^ (n & 7)) << 4));
      }
#pragma unroll
      for (int mi = 0; mi < 8; ++mi)
#pragma unroll
        for (int ni = 0; ni < 4; ++ni)
          acc[mi][ni] = __builtin_amdgcn_mfma_f32_16x16x32_bf16(af[mi], bfr[ni], acc[mi][ni], 0, 0, 0);
    }
  }

  // ---- epilogue: add cls_proj + width*w_last, map padded rows -> span index, store ----
  const float* w2p = w_lin + (size_t)(2 * Hc) * Hc; // row 2H of w_lin
  float* outp = out + Bc * Hc;                      // span_reps region
  int swb = (tile_m & 31) << 7;                     // s0*8: padded row base within batch
#pragma unroll
  for (int ni = 0; ni < 4; ++ni) {
    int h = n0 + (wid << 6) + (ni << 4) + lr;
    float cp = cls_proj[b * Hc + h];
    float w2 = w2p[h];
#pragma unroll
    for (int mi = 0; mi < 8; ++mi) {
#pragma unroll
      for (int j = 0; j < 4; ++j) {
        int m = (mi << 4) + (lq << 2) + j;
        int sw = swb + m;
        int s = sw >> 3, w = (sw & 7) + 1;
        if (s + w <= 512) {
          int nsp = (s <= 504) ? (sw)
                               : (NSPAN - (((512 - s) * (513 - s)) >> 1) + w - 1);
          size_t oidx = ((size_t)b * NSPAN + nsp) * Hc + h;
          outp[oidx] = acc[mi][ni][j] + cp + (float)w * w2;
        }
      }
    }
  }
}

extern "C" void kernel_launch(void* const* d_in, const int* in_sizes, int n_in,
                              void* d_out, int out_size, void* d_ws, size_t ws_size,
                              hipStream_t stream) {
  const float* emb = (const float*)d_in[0];
  const float* w_lin = (const float*)d_in[1];
  const float* b_lin = (const float*)d_in[2];
  unsigned short* w1t = (unsigned short*)d_ws;                   // 768*768 bf16 = 1.18 MB
  float* cls_proj = (float*)((char*)d_ws + (size_t)Hc * Hc * 2); // 16*768 f32
  float* out = (float*)d_out;

  hipLaunchKernelGGL(prep_w1t, dim3(144), dim3(256), 0, stream, w_lin, w1t);
  hipLaunchKernelGGL(cls_proj_kernel, dim3(48), dim3(256), 0, stream, emb, w_lin, b_lin, out, cls_proj);
  hipLaunchKernelGGL(span_gemm, dim3(512 * 3), dim3(256), 0, stream, emb, w1t, cls_proj, w_lin, out);
}